// Round 25
// baseline (99.000 us; speedup 1.0000x reference)
//
#include <hip/hip_runtime.h>
#include <cstdint>

constexpr int Bv = 16, Nv = 4096, Fv = 512, Sv = 8, Kv = 1024, Dv = 64;
constexpr int Mv = Bv * Nv;  // 65536 rows
#define BDIM 512
constexpr int RG = 4;        // 16-row groups per wave -> 64 rows/wave/unit

using bf16x8 = __attribute__((ext_vector_type(8))) short;
using f32x4  = __attribute__((ext_vector_type(4))) float;
typedef unsigned short u16;
typedef unsigned int u32;

__device__ __forceinline__ u16 bf16rne(float f) {
  union { float f; u32 u; } v; v.f = f;
  u32 u = v.u + 0x7FFFu + ((v.u >> 16) & 1u);
  return (u16)(u >> 16);
}

__device__ __forceinline__ u32 cvtpk(float lo, float hi) {
  u32 r;
  asm("v_cvt_pk_bf16_f32 %0, %1, %2" : "=v"(r) : "v"(lo), "v"(hi));
  return r;
}

__device__ __forceinline__ void gload_lds16(const void* g, void* lds) {
  __builtin_amdgcn_global_load_lds(
      (const __attribute__((address_space(1))) void*)g,
      (__attribute__((address_space(3))) void*)lds, 16, 0, 0);
}
__device__ __forceinline__ void gload_lds4(const void* g, void* lds) {
  __builtin_amdgcn_global_load_lds(
      (const __attribute__((address_space(1))) void*)g,
      (__attribute__((address_space(3))) void*)lds, 4, 0, 0);
}

// prep: cb fp32 -> swizzled bf16 codebook + c2m = -0.5*sum(c^2) (argmax form)
// swz layout: [s*1024+cw][slot'][8 bf16], slot' = slot ^ (cw&7)
__global__ void prep_kernel(const float* __restrict__ cb, u16* __restrict__ swz,
                            float* __restrict__ c2m) {
  int idx = blockIdx.x * 256 + threadIdx.x;  // s*1024+cw
  int cw = idx & (Kv - 1);
  const float4* src = (const float4*)(cb + (size_t)idx * Dv);
  float v[64];
  float s2 = 0.f;
#pragma unroll
  for (int i = 0; i < 16; ++i) {
    float4 f = src[i];
    v[i * 4 + 0] = f.x; v[i * 4 + 1] = f.y; v[i * 4 + 2] = f.z; v[i * 4 + 3] = f.w;
    s2 += f.x * f.x + f.y * f.y + f.z * f.z + f.w * f.w;
  }
  c2m[idx] = -0.5f * s2;
  uint4* out = (uint4*)(swz + (size_t)idx * Dv);
#pragma unroll
  for (int slot = 0; slot < 8; ++slot) {
    int slotp = slot ^ (cw & 7);
    u32 w[4];
#pragma unroll
    for (int p = 0; p < 4; ++p)
      w[p] = (u32)bf16rne(v[slot * 8 + p * 2]) | ((u32)bf16rne(v[slot * 8 + p * 2 + 1]) << 16);
    uint4 pk; pk.x = w[0]; pk.y = w[1]; pk.z = w[2]; pk.w = w[3];
    out[slotp] = pk;
  }
}

// main: R24 shell (8 waves x 1024 rows x 1 subspace, full codebook 128KB +
// c2 4KB LDS-resident staged once, launch_bounds(512,2), 4-deep buffer
// rotation, no setprio) with the K-CHAIN SPLIT ACROSS PHASES: phase t runs
// {accS[rg] = mfma(a1[t-1], xf1, accF[rg])  (finish tile t-1; accF written a
//  full phase ago) ; accF[rg] = mfma(a0[t], xf0, c2[t])  (start tile t) ;
//  ds_read tile t+3 into the buffer whose a1 was just consumed ; proc(t-1)}.
// All 8 MFMAs per phase are mutually independent -> matrix pipe streams at
// throughput (~5cyc) instead of intra-phase chain latency (~17cyc), which is
// where MfmaUtil*wall (69K cyc) vs true pipe need (20K cyc) said the time
// went. Zero vmem/barriers in the k-loop. score = <x,c> - 0.5*c2 via
// mfma(A=cb,B=x,C=c2m); lane-local argMAX, 10-bit index in low mantissa bits.
__global__ __launch_bounds__(BDIM, 2) void pq_mfma(
    const float* __restrict__ x, const float* __restrict__ cb,
    const u16* __restrict__ swz, const float* __restrict__ c2m_g,
    float* __restrict__ quant, float* __restrict__ devpart) {
  __shared__ __attribute__((aligned(16))) u16 cw_lds[Kv * Dv];  // 128KB
  __shared__ __attribute__((aligned(16))) float c2_lds[Kv];     // 4KB

  const int tid = threadIdx.x;
  const int s = blockIdx.x & 7;
  const int chunk = blockIdx.x >> 3;      // 64 chunks of 1024 rows per subspace
  const int wave = tid >> 6, lane = tid & 63;
  const int l15 = lane & 15, lg = lane >> 4;
  const int slotp0 = lg ^ (l15 & 7);       // swizzled 16B-slot, h=0 (d 0..31)
  const int slotp1 = (4 + lg) ^ (l15 & 7); // h=1 (d 32..63)

  // ---- stage the whole subspace codebook once (16 x 8KB) + c2 (2 x 2KB)
  const u16* swz_s = swz + (size_t)s * Kv * Dv;
#pragma unroll
  for (int it = 0; it < 16; ++it)
    gload_lds16(swz_s + (size_t)(it * BDIM + tid) * 8,
                &cw_lds[(it * BDIM + (tid & ~63)) * 8]);
#pragma unroll
  for (int it = 0; it < 2; ++it)
    gload_lds4(c2m_g + s * Kv + it * BDIM + tid,
               &c2_lds[it * BDIM + (tid & ~63)]);

  // ---- unit-0 x prefetch
  float4 xr[RG][4];
  {
    const float* xb = x + (size_t)(chunk * 1024 + wave * 64) * Fv + s * Dv;
#pragma unroll
    for (int rg = 0; rg < RG; ++rg) {
      const float* xp = xb + (size_t)(rg * 16 + l15) * Fv + lg * 8;
      xr[rg][0] = *(const float4*)xp;
      xr[rg][1] = *(const float4*)(xp + 4);
      xr[rg][2] = *(const float4*)(xp + 32);
      xr[rg][3] = *(const float4*)(xp + 36);
    }
  }

  __syncthreads();  // full drain: codebook + c2 staged and visible

  // lane-fixed LDS read pointers; tile t (0..63) adds t*16*Dv
  const u16* r0 = cw_lds + l15 * Dv + slotp0 * 8;
  const u16* r1 = cw_lds + l15 * Dv + slotp1 * 8;

  const u32 lgr0 = (u32)(lg * 4), lgr1 = lgr0 | 1u, lgr2 = lgr0 | 2u, lgr3 = lgr0 | 3u;
  float devx2 = 0.f, bvsum = 0.f;

#pragma unroll 1
  for (int u = 0; u < 2; ++u) {
    const int rowu = chunk * 1024 + u * 512 + wave * 64;

    // ---- xr -> bf16 fragments (cvt_pk) + lane-local x2
    bf16x8 xf[RG][2];
#pragma unroll
    for (int rg = 0; rg < RG; ++rg) {
#pragma unroll
      for (int h = 0; h < 2; ++h) {
        float4 f0 = xr[rg][h * 2], f1 = xr[rg][h * 2 + 1];
        devx2 += f0.x * f0.x + f0.y * f0.y + f0.z * f0.z + f0.w * f0.w
               + f1.x * f1.x + f1.y * f1.y + f1.z * f1.z + f1.w * f1.w;
        union { u32 w[4]; bf16x8 v; } cvt;
        cvt.w[0] = cvtpk(f0.x, f0.y);
        cvt.w[1] = cvtpk(f0.z, f0.w);
        cvt.w[2] = cvtpk(f1.x, f1.y);
        cvt.w[3] = cvtpk(f1.z, f1.w);
        xf[rg][h] = cvt.v;
      }
    }

    float bv[RG];
#pragma unroll
    for (int rg = 0; rg < RG; ++rg) bv[rg] = -3.0e38f;

    // ---- 4-deep rotation buffers + split accumulators (static — rule #20)
    bf16x8 aA0, aA1, aB0, aB1, aC0, aC1, aD0, aD1;
    f32x4 c2A, c2B, c2C, c2D;
    f32x4 accF[RG], accS[RG];

    auto readA = [&](int t) {
      aA0 = *(const bf16x8*)(r0 + t * 16 * Dv);
      aA1 = *(const bf16x8*)(r1 + t * 16 * Dv);
      c2A = *(const f32x4*)&c2_lds[t * 16 + lg * 4];
    };
    auto readB = [&](int t) {
      aB0 = *(const bf16x8*)(r0 + t * 16 * Dv);
      aB1 = *(const bf16x8*)(r1 + t * 16 * Dv);
      c2B = *(const f32x4*)&c2_lds[t * 16 + lg * 4];
    };
    auto readC = [&](int t) {
      aC0 = *(const bf16x8*)(r0 + t * 16 * Dv);
      aC1 = *(const bf16x8*)(r1 + t * 16 * Dv);
      c2C = *(const f32x4*)&c2_lds[t * 16 + lg * 4];
    };
    auto readD = [&](int t) {
      aD0 = *(const bf16x8*)(r0 + t * 16 * Dv);
      aD1 = *(const bf16x8*)(r1 + t * 16 * Dv);
      c2D = *(const f32x4*)&c2_lds[t * 16 + lg * 4];
    };
    // first-half of tile in buffer X: accF = a0X * xf0 + c2X (4 indep MFMA)
    auto mfF_A = [&]() {
#pragma unroll
      for (int rg = 0; rg < RG; ++rg)
        accF[rg] = __builtin_amdgcn_mfma_f32_16x16x32_bf16(aA0, xf[rg][0], c2A, 0, 0, 0);
    };
    auto mfF_B = [&]() {
#pragma unroll
      for (int rg = 0; rg < RG; ++rg)
        accF[rg] = __builtin_amdgcn_mfma_f32_16x16x32_bf16(aB0, xf[rg][0], c2B, 0, 0, 0);
    };
    auto mfF_C = [&]() {
#pragma unroll
      for (int rg = 0; rg < RG; ++rg)
        accF[rg] = __builtin_amdgcn_mfma_f32_16x16x32_bf16(aC0, xf[rg][0], c2C, 0, 0, 0);
    };
    auto mfF_D = [&]() {
#pragma unroll
      for (int rg = 0; rg < RG; ++rg)
        accF[rg] = __builtin_amdgcn_mfma_f32_16x16x32_bf16(aD0, xf[rg][0], c2D, 0, 0, 0);
    };
    // second-half of PREVIOUS tile (a1 from its buffer): accS = a1 * xf1 + accF
    auto mfS_A = [&]() {
#pragma unroll
      for (int rg = 0; rg < RG; ++rg)
        accS[rg] = __builtin_amdgcn_mfma_f32_16x16x32_bf16(aA1, xf[rg][1], accF[rg], 0, 0, 0);
    };
    auto mfS_B = [&]() {
#pragma unroll
      for (int rg = 0; rg < RG; ++rg)
        accS[rg] = __builtin_amdgcn_mfma_f32_16x16x32_bf16(aB1, xf[rg][1], accF[rg], 0, 0, 0);
    };
    auto mfS_C = [&]() {
#pragma unroll
      for (int rg = 0; rg < RG; ++rg)
        accS[rg] = __builtin_amdgcn_mfma_f32_16x16x32_bf16(aC1, xf[rg][1], accF[rg], 0, 0, 0);
    };
    auto mfS_D = [&]() {
#pragma unroll
      for (int rg = 0; rg < RG; ++rg)
        accS[rg] = __builtin_amdgcn_mfma_f32_16x16x32_bf16(aD1, xf[rg][1], accF[rg], 0, 0, 0);
    };
    auto proc = [&](u32 tb) {  // completed tile tb>>4 from accS
#pragma unroll
      for (int rg = 0; rg < RG; ++rg) {
        float p0 = __builtin_bit_cast(float, (__builtin_bit_cast(u32, accS[rg][0]) | tb) | lgr0);
        float p1 = __builtin_bit_cast(float, (__builtin_bit_cast(u32, accS[rg][1]) | tb) | lgr1);
        float p2 = __builtin_bit_cast(float, (__builtin_bit_cast(u32, accS[rg][2]) | tb) | lgr2);
        float p3 = __builtin_bit_cast(float, (__builtin_bit_cast(u32, accS[rg][3]) | tb) | lgr3);
        float m = fmaxf(fmaxf(p0, p1), p2);
        bv[rg] = fmaxf(fmaxf(m, p3), bv[rg]);
      }
    };

    // ---- k-loop: 64 tiles; phase t = {mfS(t-1 buf); mfF(t buf);
    // read(t+3) into the buffer whose a1 was just consumed; proc(t-1)}.
    readA(0); readB(1); readC(2);
    mfF_A(); readD(3);                               // phase 0
#pragma unroll 1
    for (int k = 0; k < 14; ++k) {                   // phases 4k+1 .. 4k+4
      const int t = 4 * k;
      mfS_A(); mfF_B(); readA(t + 4); proc((u32)(t << 4));
      mfS_B(); mfF_C(); readB(t + 5); proc((u32)((t + 1) << 4));
      mfS_C(); mfF_D(); readC(t + 6); proc((u32)((t + 2) << 4));
      mfS_D(); mfF_A(); readD(t + 7); proc((u32)((t + 3) << 4));
    }
    // phases 57..60 (reads 60..63), then 61..63, then final finish of 63
    mfS_A(); mfF_B(); readA(60); proc(56u << 4);
    mfS_B(); mfF_C(); readB(61); proc(57u << 4);
    mfS_C(); mfF_D(); readC(62); proc(58u << 4);
    mfS_D(); mfF_A(); readD(63); proc(59u << 4);
    mfS_A(); mfF_B(); proc(60u << 4);
    mfS_B(); mfF_C(); proc(61u << 4);
    mfS_C(); mfF_D(); proc(62u << 4);
    mfS_D(); proc(63u << 4);

    // ---- cross-lane max over the 4 lg groups (rows preserved in l15)
#pragma unroll
    for (int rg = 0; rg < RG; ++rg) {
      float b = bv[rg];
      b = fmaxf(b, __shfl_xor(b, 16, 64));
      b = fmaxf(b, __shfl_xor(b, 32, 64));
      bv[rg] = b;
      bvsum += b;
    }

    // ---- issue next unit's x loads BEFORE the epilogue (hide under it)
    if (u == 0) {
      const float* xb = x + (size_t)(chunk * 1024 + 512 + wave * 64) * Fv + s * Dv;
#pragma unroll
      for (int rg = 0; rg < RG; ++rg) {
        const float* xp = xb + (size_t)(rg * 16 + l15) * Fv + lg * 8;
        xr[rg][0] = *(const float4*)xp;
        xr[rg][1] = *(const float4*)(xp + 4);
        xr[rg][2] = *(const float4*)(xp + 32);
        xr[rg][3] = *(const float4*)(xp + 36);
      }
    }

    // ---- coalesced quant gather/write: iter i covers rows i*4+lg; index
    // shfl'd from the lane holding that row; k = low 10 bits of packed max
    const float* cbs = cb + (size_t)s * Kv * Dv;
    float* qbase = quant + (size_t)rowu * Fv + s * Dv;
#pragma unroll
    for (int i = 0; i < 16; ++i) {
      int rl = i * 4 + lg;
      int kk = __shfl(__builtin_bit_cast(int, bv[i >> 2]), 4 * (i & 3) + lg, 64) & 1023;
      f32x4 v = *(const f32x4*)(cbs + (size_t)kk * Dv + l15 * 4);
      __builtin_nontemporal_store(v, (f32x4*)(qbase + (size_t)rl * Fv + l15 * 4));
    }
  }

  // ---- dev partial: sum x2 over all lanes; bv identical across lg -> mask 1..8
#pragma unroll
  for (int m = 1; m <= 32; m <<= 1) devx2 += __shfl_xor(devx2, m, 64);
#pragma unroll
  for (int m = 1; m <= 8; m <<= 1) bvsum += __shfl_xor(bvsum, m, 64);
  if (lane == 0)
    devpart[(size_t)blockIdx.x * 8 + wave] = devx2 - 2.f * bvsum;
}

// deterministic final reduction of 4096 wave partials -> dev scalar
__global__ void dev_reduce(const float* __restrict__ part, float* __restrict__ out) {
  __shared__ float sred[256];
  int tid = threadIdx.x;
  float s = 0.f;
  for (int i = tid; i < 4096; i += 256) s += part[i];
  sred[tid] = s;
  __syncthreads();
  for (int off = 128; off > 0; off >>= 1) {
    if (tid < off) sred[tid] += sred[tid + off];
    __syncthreads();
  }
  if (tid == 0) out[0] = sred[0] * (1.25f / 4194304.0f);
}

extern "C" void kernel_launch(void* const* d_in, const int* in_sizes, int n_in,
                              void* d_out, int out_size, void* d_ws, size_t ws_size,
                              hipStream_t stream) {
  const float* x = (const float*)d_in[0];   // (B,N,F) fp32
  const float* cb = (const float*)d_in[1];  // (S,K,D) fp32
  float* quant = (float*)d_out;
  float* dev = quant + (size_t)Mv * Fv;

  // ws: swz bf16 codebook (1MB), c2m (32KB), dev partials (16KB)
  u16* swz = (u16*)d_ws;
  float* c2m = (float*)(swz + (size_t)Sv * Kv * Dv);
  float* part = c2m + Sv * Kv;

  prep_kernel<<<(Sv * Kv) / 256, 256, 0, stream>>>(cb, swz, c2m);
  pq_mfma<<<512, BDIM, 0, stream>>>(x, cb, swz, c2m, quant, part);
  dev_reduce<<<1, 256, 0, stream>>>(part, dev);
}

// Round 26
// 94.137 us; speedup vs baseline: 1.0517x; 1.0517x over previous
//
#include <hip/hip_runtime.h>
#include <cstdint>

constexpr int Bv = 16, Nv = 4096, Fv = 512, Sv = 8, Kv = 1024, Dv = 64;
constexpr int Mv = Bv * Nv;  // 65536 rows
#define BDIM 512
constexpr int RG = 4;        // 16-row groups per wave -> 64 rows/wave/unit

using bf16x8 = __attribute__((ext_vector_type(8))) short;
using f32x4  = __attribute__((ext_vector_type(4))) float;
typedef unsigned short u16;
typedef unsigned int u32;

__device__ __forceinline__ u16 bf16rne(float f) {
  union { float f; u32 u; } v; v.f = f;
  u32 u = v.u + 0x7FFFu + ((v.u >> 16) & 1u);
  return (u16)(u >> 16);
}

__device__ __forceinline__ u32 cvtpk(float lo, float hi) {
  u32 r;
  asm("v_cvt_pk_bf16_f32 %0, %1, %2" : "=v"(r) : "v"(lo), "v"(hi));
  return r;
}

__device__ __forceinline__ void gload_lds16(const void* g, void* lds) {
  __builtin_amdgcn_global_load_lds(
      (const __attribute__((address_space(1))) void*)g,
      (__attribute__((address_space(3))) void*)lds, 16, 0, 0);
}
__device__ __forceinline__ void gload_lds4(const void* g, void* lds) {
  __builtin_amdgcn_global_load_lds(
      (const __attribute__((address_space(1))) void*)g,
      (__attribute__((address_space(3))) void*)lds, 4, 0, 0);
}

// prep: cb fp32 -> swizzled bf16 codebook + c2m = -0.5*sum(c^2) (argmax form)
// swz layout: [s*1024+cw][slot'][8 bf16], slot' = slot ^ (cw&7)
__global__ void prep_kernel(const float* __restrict__ cb, u16* __restrict__ swz,
                            float* __restrict__ c2m) {
  int idx = blockIdx.x * 256 + threadIdx.x;  // s*1024+cw
  int cw = idx & (Kv - 1);
  const float4* src = (const float4*)(cb + (size_t)idx * Dv);
  float v[64];
  float s2 = 0.f;
#pragma unroll
  for (int i = 0; i < 16; ++i) {
    float4 f = src[i];
    v[i * 4 + 0] = f.x; v[i * 4 + 1] = f.y; v[i * 4 + 2] = f.z; v[i * 4 + 3] = f.w;
    s2 += f.x * f.x + f.y * f.y + f.z * f.z + f.w * f.w;
  }
  c2m[idx] = -0.5f * s2;
  uint4* out = (uint4*)(swz + (size_t)idx * Dv);
#pragma unroll
  for (int slot = 0; slot < 8; ++slot) {
    int slotp = slot ^ (cw & 7);
    u32 w[4];
#pragma unroll
    for (int p = 0; p < 4; ++p)
      w[p] = (u32)bf16rne(v[slot * 8 + p * 2]) | ((u32)bf16rne(v[slot * 8 + p * 2 + 1]) << 16);
    uint4 pk; pk.x = w[0]; pk.y = w[1]; pk.z = w[2]; pk.w = w[3];
    out[slotp] = pk;
  }
}

// main (session-best configuration, R24): block = 8 waves x 1024 rows x 1
// subspace; full codebook 128KB + c2 4KB LDS-resident staged once;
// launch_bounds(512,2) — the ONLY no-spill config for this body (all other
// bounds collapse the allocator to a 64-VGPR fit and spill). 4-deep buffer
// rotation: phase t = {mfma(t); ds_read(t+4); proc(t)} — 4 tiles in flight
// per wave, read-to-consume distance ~4 phases; no setprio (lockstep waves,
// m190). Zero vmem/barriers in the k-loop. score = <x,c> - 0.5*c2 via
// mfma(A=cb,B=x,C=c2m); lane-local argMAX with the 10-bit codeword index
// OR'd into the score's low mantissa bits (perturbation ~1e-7, covered by
// the 2/K quant bound). Coalesced 256B gather/write epilogue; deterministic
// two-stage dev reduction.
__global__ __launch_bounds__(BDIM, 2) void pq_mfma(
    const float* __restrict__ x, const float* __restrict__ cb,
    const u16* __restrict__ swz, const float* __restrict__ c2m_g,
    float* __restrict__ quant, float* __restrict__ devpart) {
  __shared__ __attribute__((aligned(16))) u16 cw_lds[Kv * Dv];  // 128KB
  __shared__ __attribute__((aligned(16))) float c2_lds[Kv];     // 4KB

  const int tid = threadIdx.x;
  const int s = blockIdx.x & 7;
  const int chunk = blockIdx.x >> 3;      // 64 chunks of 1024 rows per subspace
  const int wave = tid >> 6, lane = tid & 63;
  const int l15 = lane & 15, lg = lane >> 4;
  const int slotp0 = lg ^ (l15 & 7);       // swizzled 16B-slot, h=0 (d 0..31)
  const int slotp1 = (4 + lg) ^ (l15 & 7); // h=1 (d 32..63)

  // ---- stage the whole subspace codebook once (16 x 8KB) + c2 (2 x 2KB)
  const u16* swz_s = swz + (size_t)s * Kv * Dv;
#pragma unroll
  for (int it = 0; it < 16; ++it)
    gload_lds16(swz_s + (size_t)(it * BDIM + tid) * 8,
                &cw_lds[(it * BDIM + (tid & ~63)) * 8]);
#pragma unroll
  for (int it = 0; it < 2; ++it)
    gload_lds4(c2m_g + s * Kv + it * BDIM + tid,
               &c2_lds[it * BDIM + (tid & ~63)]);

  // ---- unit-0 x prefetch
  float4 xr[RG][4];
  {
    const float* xb = x + (size_t)(chunk * 1024 + wave * 64) * Fv + s * Dv;
#pragma unroll
    for (int rg = 0; rg < RG; ++rg) {
      const float* xp = xb + (size_t)(rg * 16 + l15) * Fv + lg * 8;
      xr[rg][0] = *(const float4*)xp;
      xr[rg][1] = *(const float4*)(xp + 4);
      xr[rg][2] = *(const float4*)(xp + 32);
      xr[rg][3] = *(const float4*)(xp + 36);
    }
  }

  __syncthreads();  // full drain: codebook + c2 staged and visible

  // lane-fixed LDS read pointers; tile t (0..63) adds t*16*Dv
  const u16* r0 = cw_lds + l15 * Dv + slotp0 * 8;
  const u16* r1 = cw_lds + l15 * Dv + slotp1 * 8;

  const u32 lgr0 = (u32)(lg * 4), lgr1 = lgr0 | 1u, lgr2 = lgr0 | 2u, lgr3 = lgr0 | 3u;
  float devx2 = 0.f, bvsum = 0.f;

#pragma unroll 1
  for (int u = 0; u < 2; ++u) {
    const int rowu = chunk * 1024 + u * 512 + wave * 64;

    // ---- xr -> bf16 fragments (cvt_pk) + lane-local x2
    bf16x8 xf[RG][2];
#pragma unroll
    for (int rg = 0; rg < RG; ++rg) {
#pragma unroll
      for (int h = 0; h < 2; ++h) {
        float4 f0 = xr[rg][h * 2], f1 = xr[rg][h * 2 + 1];
        devx2 += f0.x * f0.x + f0.y * f0.y + f0.z * f0.z + f0.w * f0.w
               + f1.x * f1.x + f1.y * f1.y + f1.z * f1.z + f1.w * f1.w;
        union { u32 w[4]; bf16x8 v; } cvt;
        cvt.w[0] = cvtpk(f0.x, f0.y);
        cvt.w[1] = cvtpk(f0.z, f0.w);
        cvt.w[2] = cvtpk(f1.x, f1.y);
        cvt.w[3] = cvtpk(f1.z, f1.w);
        xf[rg][h] = cvt.v;
      }
    }

    float bv[RG];
#pragma unroll
    for (int rg = 0; rg < RG; ++rg) bv[rg] = -3.0e38f;

    // ---- 4-deep rotation buffers (static names — rule #20) + single acc set
    bf16x8 aA0, aA1, aB0, aB1, aC0, aC1, aD0, aD1;
    f32x4 c2A, c2B, c2C, c2D;
    f32x4 acc[RG];

    auto readA = [&](int t) {
      aA0 = *(const bf16x8*)(r0 + t * 16 * Dv);
      aA1 = *(const bf16x8*)(r1 + t * 16 * Dv);
      c2A = *(const f32x4*)&c2_lds[t * 16 + lg * 4];
    };
    auto readB = [&](int t) {
      aB0 = *(const bf16x8*)(r0 + t * 16 * Dv);
      aB1 = *(const bf16x8*)(r1 + t * 16 * Dv);
      c2B = *(const f32x4*)&c2_lds[t * 16 + lg * 4];
    };
    auto readC = [&](int t) {
      aC0 = *(const bf16x8*)(r0 + t * 16 * Dv);
      aC1 = *(const bf16x8*)(r1 + t * 16 * Dv);
      c2C = *(const f32x4*)&c2_lds[t * 16 + lg * 4];
    };
    auto readD = [&](int t) {
      aD0 = *(const bf16x8*)(r0 + t * 16 * Dv);
      aD1 = *(const bf16x8*)(r1 + t * 16 * Dv);
      c2D = *(const f32x4*)&c2_lds[t * 16 + lg * 4];
    };
    auto mfmaA = [&]() {
#pragma unroll
      for (int rg = 0; rg < RG; ++rg)
        acc[rg] = __builtin_amdgcn_mfma_f32_16x16x32_bf16(aA0, xf[rg][0], c2A, 0, 0, 0);
#pragma unroll
      for (int rg = 0; rg < RG; ++rg)
        acc[rg] = __builtin_amdgcn_mfma_f32_16x16x32_bf16(aA1, xf[rg][1], acc[rg], 0, 0, 0);
    };
    auto mfmaB = [&]() {
#pragma unroll
      for (int rg = 0; rg < RG; ++rg)
        acc[rg] = __builtin_amdgcn_mfma_f32_16x16x32_bf16(aB0, xf[rg][0], c2B, 0, 0, 0);
#pragma unroll
      for (int rg = 0; rg < RG; ++rg)
        acc[rg] = __builtin_amdgcn_mfma_f32_16x16x32_bf16(aB1, xf[rg][1], acc[rg], 0, 0, 0);
    };
    auto mfmaC = [&]() {
#pragma unroll
      for (int rg = 0; rg < RG; ++rg)
        acc[rg] = __builtin_amdgcn_mfma_f32_16x16x32_bf16(aC0, xf[rg][0], c2C, 0, 0, 0);
#pragma unroll
      for (int rg = 0; rg < RG; ++rg)
        acc[rg] = __builtin_amdgcn_mfma_f32_16x16x32_bf16(aC1, xf[rg][1], acc[rg], 0, 0, 0);
    };
    auto mfmaD = [&]() {
#pragma unroll
      for (int rg = 0; rg < RG; ++rg)
        acc[rg] = __builtin_amdgcn_mfma_f32_16x16x32_bf16(aD0, xf[rg][0], c2D, 0, 0, 0);
#pragma unroll
      for (int rg = 0; rg < RG; ++rg)
        acc[rg] = __builtin_amdgcn_mfma_f32_16x16x32_bf16(aD1, xf[rg][1], acc[rg], 0, 0, 0);
    };
    auto proc = [&](u32 tb) {  // tb = tile<<4 (wave-uniform SGPR)
#pragma unroll
      for (int rg = 0; rg < RG; ++rg) {
        float p0 = __builtin_bit_cast(float, (__builtin_bit_cast(u32, acc[rg][0]) | tb) | lgr0);
        float p1 = __builtin_bit_cast(float, (__builtin_bit_cast(u32, acc[rg][1]) | tb) | lgr1);
        float p2 = __builtin_bit_cast(float, (__builtin_bit_cast(u32, acc[rg][2]) | tb) | lgr2);
        float p3 = __builtin_bit_cast(float, (__builtin_bit_cast(u32, acc[rg][3]) | tb) | lgr3);
        float m = fmaxf(fmaxf(p0, p1), p2);
        bv[rg] = fmaxf(fmaxf(m, p3), bv[rg]);
      }
    };

    // ---- k-loop: 64 tiles; per phase {mfmaX(t); readX(t+4); proc(t)} —
    // readX(t) consumed 4 phases (~400cyc) later; 4 tiles in flight/wave
    readA(0); readB(1); readC(2); readD(3);
#pragma unroll 1
    for (int k = 0; k < 14; ++k) {
      const int t = 4 * k;
      mfmaA(); readA(t + 4); proc((u32)(t << 4));
      mfmaB(); readB(t + 5); proc((u32)((t + 1) << 4));
      mfmaC(); readC(t + 6); proc((u32)((t + 2) << 4));
      mfmaD(); readD(t + 7); proc((u32)((t + 3) << 4));
    }
    // after loop: buffers hold A=56,B=57,C=58,D=59; reads issued to 59
    mfmaA(); readA(60); proc(56u << 4);
    mfmaB(); readB(61); proc(57u << 4);
    mfmaC(); readC(62); proc(58u << 4);
    mfmaD(); readD(63); proc(59u << 4);
    mfmaA(); proc(60u << 4);
    mfmaB(); proc(61u << 4);
    mfmaC(); proc(62u << 4);
    mfmaD(); proc(63u << 4);

    // ---- cross-lane max over the 4 lg groups (rows preserved in l15)
#pragma unroll
    for (int rg = 0; rg < RG; ++rg) {
      float b = bv[rg];
      b = fmaxf(b, __shfl_xor(b, 16, 64));
      b = fmaxf(b, __shfl_xor(b, 32, 64));
      bv[rg] = b;
      bvsum += b;
    }

    // ---- issue next unit's x loads BEFORE the epilogue (hide under it)
    if (u == 0) {
      const float* xb = x + (size_t)(chunk * 1024 + 512 + wave * 64) * Fv + s * Dv;
#pragma unroll
      for (int rg = 0; rg < RG; ++rg) {
        const float* xp = xb + (size_t)(rg * 16 + l15) * Fv + lg * 8;
        xr[rg][0] = *(const float4*)xp;
        xr[rg][1] = *(const float4*)(xp + 4);
        xr[rg][2] = *(const float4*)(xp + 32);
        xr[rg][3] = *(const float4*)(xp + 36);
      }
    }

    // ---- coalesced quant gather/write: iter i covers rows i*4+lg; index
    // shfl'd from the lane holding that row; k = low 10 bits of packed max
    const float* cbs = cb + (size_t)s * Kv * Dv;
    float* qbase = quant + (size_t)rowu * Fv + s * Dv;
#pragma unroll
    for (int i = 0; i < 16; ++i) {
      int rl = i * 4 + lg;
      int kk = __shfl(__builtin_bit_cast(int, bv[i >> 2]), 4 * (i & 3) + lg, 64) & 1023;
      f32x4 v = *(const f32x4*)(cbs + (size_t)kk * Dv + l15 * 4);
      __builtin_nontemporal_store(v, (f32x4*)(qbase + (size_t)rl * Fv + l15 * 4));
    }
  }

  // ---- dev partial: sum x2 over all lanes; bv identical across lg -> mask 1..8
#pragma unroll
  for (int m = 1; m <= 32; m <<= 1) devx2 += __shfl_xor(devx2, m, 64);
#pragma unroll
  for (int m = 1; m <= 8; m <<= 1) bvsum += __shfl_xor(bvsum, m, 64);
  if (lane == 0)
    devpart[(size_t)blockIdx.x * 8 + wave] = devx2 - 2.f * bvsum;
}

// deterministic final reduction of 4096 wave partials -> dev scalar
__global__ void dev_reduce(const float* __restrict__ part, float* __restrict__ out) {
  __shared__ float sred[256];
  int tid = threadIdx.x;
  float s = 0.f;
  for (int i = tid; i < 4096; i += 256) s += part[i];
  sred[tid] = s;
  __syncthreads();
  for (int off = 128; off > 0; off >>= 1) {
    if (tid < off) sred[tid] += sred[tid + off];
    __syncthreads();
  }
  if (tid == 0) out[0] = sred[0] * (1.25f / 4194304.0f);
}

extern "C" void kernel_launch(void* const* d_in, const int* in_sizes, int n_in,
                              void* d_out, int out_size, void* d_ws, size_t ws_size,
                              hipStream_t stream) {
  const float* x = (const float*)d_in[0];   // (B,N,F) fp32
  const float* cb = (const float*)d_in[1];  // (S,K,D) fp32
  float* quant = (float*)d_out;
  float* dev = quant + (size_t)Mv * Fv;

  // ws: swz bf16 codebook (1MB), c2m (32KB), dev partials (16KB)
  u16* swz = (u16*)d_ws;
  float* c2m = (float*)(swz + (size_t)Sv * Kv * Dv);
  float* part = c2m + Sv * Kv;

  prep_kernel<<<(Sv * Kv) / 256, 256, 0, stream>>>(cb, swz, c2m);
  pq_mfma<<<512, BDIM, 0, stream>>>(x, cb, swz, c2m, quant, part);
  dev_reduce<<<1, 256, 0, stream>>>(part, dev);
}